// Round 3
// baseline (213.903 us; speedup 1.0000x reference)
//
#include <hip/hip_runtime.h>
#include <hip/hip_cooperative_groups.h>
#include <math.h>

namespace cg = cooperative_groups;

#define NN 384
#define NT 24              // NN/16
#define NTILES (NT * NT)   // 576 blocks, 1 wave each

typedef __attribute__((ext_vector_type(8))) short short8;          // 8 bf16
typedef __attribute__((ext_vector_type(4))) float v4f;             // 4 fp32 acc
typedef __attribute__((ext_vector_type(4))) unsigned short ushort4v;

__device__ __forceinline__ unsigned short f2bf(float f) {
    union { float f; unsigned u; } v; v.f = f;
    return (unsigned short)((v.u + 0x7FFFu + ((v.u >> 16) & 1u)) >> 16);
}
__device__ __forceinline__ float bf2f(unsigned short h) {
    union { unsigned u; float f; } v; v.u = ((unsigned)h) << 16;
    return v.f;
}

// One cooperative kernel, 3 phases separated by grid syncs:
//   A: P16[i,j] = bf16(exp(-lam*dist) gated by adj, i!=j); PT16 = P^T
//   B: S = P*P (MFMA, global-direct frags); V = od/(P+S) gated; V16/VT16/V32
//   C: out = p_exact * (V + V*P^T + P^T*V)
__global__ __launch_bounds__(64) void fused_kernel(
    const float* __restrict__ od, const int* __restrict__ adj,
    const float* __restrict__ dist, const int* __restrict__ lam_ptr,
    float* __restrict__ out,
    unsigned short* __restrict__ P16, unsigned short* __restrict__ PT16,
    unsigned short* __restrict__ V16, unsigned short* __restrict__ VT16,
    float* __restrict__ V32)
{
    cg::grid_group grid = cg::this_grid();
    const int lane = threadIdx.x;
    const int blk = blockIdx.x;
    const float lam = (float)(*lam_ptr);
    const int i0 = (blk / NT) * 16, j0 = (blk % NT) * 16;
    const int col = lane & 15, quad = lane >> 4;

    // ---- Phase A: build P16 / PT16 (4 contiguous elems per thread) ----
    {
        int base = (blk * 64 + lane) * 4;      // covers exactly NN*NN
        int i = base / NN;                     // NN%4==0 -> same row for all 4
        int j = base - i * NN;
        float4 d4 = *(const float4*)(dist + base);
        int4   a4 = *(const int4*)(adj + base);
        float dv[4] = {d4.x, d4.y, d4.z, d4.w};
        int   av[4] = {a4.x, a4.y, a4.z, a4.w};
        ushort4v h;
#pragma unroll
        for (int e = 0; e < 4; ++e) {
            float p = (av[e] > 0 && i != (j + e)) ? expf(-lam * dv[e]) : 0.0f;
            unsigned short hb = f2bf(p);
            h[e] = hb;
            PT16[(j + e) * NN + i] = hb;
        }
        *(ushort4v*)(P16 + base) = h;          // 8 B store
    }

    grid.sync();

    // ---- Phase B: S = P*P tile; V = od/(P+S) ----
    {
        v4f acc = {0.f, 0.f, 0.f, 0.f};
        const short8* arow = (const short8*)(P16 + (i0 + col) * NN + quad * 8);
        const short8* brow = (const short8*)(PT16 + (j0 + col) * NN + quad * 8);
#pragma unroll
        for (int k0 = 0; k0 < NN / 32; ++k0) {
            short8 a = arow[k0 * 4];
            short8 b = brow[k0 * 4];
            acc = __builtin_amdgcn_mfma_f32_16x16x32_bf16(a, b, acc, 0, 0, 0);
        }
#pragma unroll
        for (int r = 0; r < 4; ++r) {
            int i = i0 + quad * 4 + r, j = j0 + col;
            int idx = i * NN + j;
            float denom = bf2f(P16[idx]) + acc[r];
            float o = od[idx];
            float v = (i != j && o > 0.0f && denom > 0.0f) ? o / denom : 0.0f;
            V32[idx] = v;
            unsigned short hb = f2bf(v);
            V16[idx] = hb;
            VT16[j * NN + i] = hb;
        }
    }

    grid.sync();

    // ---- Phase C: out = p_exact * (V + V*P^T + P^T*V) ----
    {
        v4f accW = {0.f, 0.f, 0.f, 0.f};
        v4f accU = {0.f, 0.f, 0.f, 0.f};
        const short8* aW = (const short8*)(V16 + (i0 + col) * NN + quad * 8);
        const short8* bW = (const short8*)(P16 + (j0 + col) * NN + quad * 8);
        const short8* aU = (const short8*)(PT16 + (i0 + col) * NN + quad * 8);
        const short8* bU = (const short8*)(VT16 + (j0 + col) * NN + quad * 8);
#pragma unroll
        for (int k0 = 0; k0 < NN / 32; ++k0) {
            short8 a0 = aW[k0 * 4];
            short8 b0 = bW[k0 * 4];
            short8 a1 = aU[k0 * 4];
            short8 b1 = bU[k0 * 4];
            accW = __builtin_amdgcn_mfma_f32_16x16x32_bf16(a0, b0, accW, 0, 0, 0);
            accU = __builtin_amdgcn_mfma_f32_16x16x32_bf16(a1, b1, accU, 0, 0, 0);
        }
#pragma unroll
        for (int r = 0; r < 4; ++r) {
            int i = i0 + quad * 4 + r, j = j0 + col;
            int idx = i * NN + j;
            float p = (adj[idx] > 0 && i != j) ? expf(-lam * dist[idx]) : 0.0f;
            out[idx] = p * (V32[idx] + accW[r] + accU[r]);
        }
    }
}

extern "C" void kernel_launch(void* const* d_in, const int* in_sizes, int n_in,
                              void* d_out, int out_size, void* d_ws, size_t ws_size,
                              hipStream_t stream) {
    const float* od   = (const float*)d_in[0];
    const int*   adj  = (const int*)d_in[1];
    const float* dist = (const float*)d_in[2];
    const int*   lam  = (const int*)d_in[3];
    // d_in[4] = capacity (unused: max_iter=1, BPR update is post-output)
    float* out = (float*)d_out;

    unsigned short* P16  = (unsigned short*)d_ws;
    unsigned short* PT16 = P16 + NN * NN;
    unsigned short* V16  = PT16 + NN * NN;
    unsigned short* VT16 = V16 + NN * NN;
    float*          V32  = (float*)(VT16 + NN * NN);

    void* args[] = {(void*)&od, (void*)&adj, (void*)&dist, (void*)&lam,
                    (void*)&out, (void*)&P16, (void*)&PT16, (void*)&V16,
                    (void*)&VT16, (void*)&V32};
    hipLaunchCooperativeKernel((const void*)fused_kernel, dim3(NTILES), dim3(64),
                               args, 0, stream);
}

// Round 4
// 126.543 us; speedup vs baseline: 1.6904x; 1.6904x over previous
//
#include <hip/hip_runtime.h>
#include <math.h>

#define NN 384
#define NT 24              // NN/16
#define NTILES (NT * NT)   // 576
#define LDSW 392           // padded LDS row stride (bf16 elems); 392*2=784B, 16B-aligned

typedef __attribute__((ext_vector_type(8))) short short8;          // 8 bf16
typedef __attribute__((ext_vector_type(4))) float v4f;             // 4 fp32
typedef __attribute__((ext_vector_type(4))) unsigned short ushort4v;

__device__ __forceinline__ unsigned short f2bf(float f) {
    union { float f; unsigned u; } v; v.f = f;
    return (unsigned short)((v.u + 0x7FFFu + ((v.u >> 16) & 1u)) >> 16);
}
__device__ __forceinline__ float bf2f(unsigned short h) {
    union { unsigned u; float f; } v; v.u = ((unsigned)h) << 16;
    return v.f;
}

// K1: P16[i,j] = bf16(exp(-lam*dist) gated by adj, i!=j); PT16 = P^T.
// 576 blocks x 256 threads = exactly NN*NN.
__global__ void build_p_kernel(const int* __restrict__ adj,
                               const float* __restrict__ dist,
                               const int* __restrict__ lam_ptr,
                               unsigned short* __restrict__ P16,
                               unsigned short* __restrict__ PT16) {
    int idx = blockIdx.x * 256 + threadIdx.x;
    int i = idx / NN;
    int j = idx - i * NN;
    float lam = (float)(*lam_ptr);
    float p = (adj[idx] > 0 && i != j) ? expf(-lam * dist[idx]) : 0.0f;
    unsigned short h = f2bf(p);
    P16[idx] = h;
    PT16[j * NN + i] = h;
}

// K2: one block (4 waves) per 16x16 output tile. Redundantly computes the
// V rows/cols this tile needs (strip GEMMs split over waves), stages them in
// LDS, then wave 0 computes W = V*P^T and U = P^T*V tiles + epilogue.
__global__ __launch_bounds__(256) void fused_tile_kernel(
    const unsigned short* __restrict__ P16,
    const unsigned short* __restrict__ PT16,
    const float* __restrict__ od,
    const int* __restrict__ adj,
    const float* __restrict__ dist,
    const int* __restrict__ lam_ptr,
    float* __restrict__ out)
{
    __shared__ __align__(16) unsigned short Vr[16][LDSW];   // V[i0+r][d], bf16
    __shared__ __align__(16) unsigned short VcT[16][LDSW];  // V[o][j0+c] at [c][o], bf16
    __shared__ float Vd[16][17];                            // fp32 direct tile V[i0:16, j0:16]

    const int t = blockIdx.x;
    const int it = t / NT, jt = t % NT;
    const int i0 = it * 16, j0 = jt * 16;
    const int tid = threadIdx.x;
    const int wave = tid >> 6;
    const int lane = tid & 63;
    const int col = lane & 15, quad = lane >> 4;

    // Preload invariant fragments:
    //  a1[k] : A-frag of P rows i0:16  (GEMM1 A, also U's A comes from PT rows i0)
    //  b2[k] : B-frag of P cols j0:16  (= PT16 rows j0:16) (GEMM2 B)
    short8 a1[12], b2[12];
#pragma unroll
    for (int k0 = 0; k0 < 12; ++k0) {
        a1[k0] = *(const short8*)(P16 + (i0 + col) * NN + k0 * 32 + quad * 8);
        b2[k0] = *(const short8*)(PT16 + (j0 + col) * NN + k0 * 32 + quad * 8);
    }

    // ---- GEMM1: V rows i0:16 (S = P[i0:16,:] @ P), n-tiles split across waves ----
    for (int n0 = wave * 6; n0 < wave * 6 + 6; ++n0) {
        v4f acc = {0.f, 0.f, 0.f, 0.f};
#pragma unroll
        for (int k0 = 0; k0 < 12; ++k0) {
            short8 b = *(const short8*)(PT16 + (n0 * 16 + col) * NN + k0 * 32 + quad * 8);
            acc = __builtin_amdgcn_mfma_f32_16x16x32_bf16(a1[k0], b, acc, 0, 0, 0);
        }
#pragma unroll
        for (int r = 0; r < 4; ++r) {
            int i = i0 + quad * 4 + r, j = n0 * 16 + col;
            int idx = i * NN + j;
            float denom = bf2f(P16[idx]) + acc[r];
            float o = od[idx];
            float v = (i != j && o > 0.f && denom > 0.f)
                          ? o * __builtin_amdgcn_rcpf(denom) : 0.f;
            Vr[quad * 4 + r][j] = f2bf(v);
            if (n0 == jt) Vd[quad * 4 + r][col] = v;   // exact fp32 direct term
        }
    }

    // ---- GEMM2: V cols j0:16 (S = P @ P[:,j0:16]), m-tiles split across waves ----
    for (int m0 = wave * 6; m0 < wave * 6 + 6; ++m0) {
        v4f acc = {0.f, 0.f, 0.f, 0.f};
#pragma unroll
        for (int k0 = 0; k0 < 12; ++k0) {
            short8 a = *(const short8*)(P16 + (m0 * 16 + col) * NN + k0 * 32 + quad * 8);
            acc = __builtin_amdgcn_mfma_f32_16x16x32_bf16(a, b2[k0], acc, 0, 0, 0);
        }
#pragma unroll
        for (int r = 0; r < 4; ++r) {
            int i = m0 * 16 + quad * 4 + r, j = j0 + col;
            int idx = i * NN + j;
            float denom = bf2f(P16[idx]) + acc[r];
            float o = od[idx];
            float v = (i != j && o > 0.f && denom > 0.f)
                          ? o * __builtin_amdgcn_rcpf(denom) : 0.f;
            VcT[col][i] = f2bf(v);
        }
    }

    __syncthreads();

    // ---- Wave 0: W tile (V*P^T), U tile (P^T*V), epilogue ----
    if (wave == 0) {
        v4f accW = {0.f, 0.f, 0.f, 0.f};
        v4f accU = {0.f, 0.f, 0.f, 0.f};
#pragma unroll
        for (int k0 = 0; k0 < 12; ++k0) {
            // W[i,j] = sum_d V[i,d]*P[j,d]: A = V rows (LDS), B^T = P rows j (global)
            short8 aW = *(const short8*)(&Vr[col][k0 * 32 + quad * 8]);
            short8 bW = *(const short8*)(P16 + (j0 + col) * NN + k0 * 32 + quad * 8);
            accW = __builtin_amdgcn_mfma_f32_16x16x32_bf16(aW, bW, accW, 0, 0, 0);
            // U[i,j] = sum_o P[o,i]*V[o,j]: A = PT rows i (global), B = V cols (LDS)
            short8 aU = *(const short8*)(PT16 + (i0 + col) * NN + k0 * 32 + quad * 8);
            short8 bU = *(const short8*)(&VcT[col][k0 * 32 + quad * 8]);
            accU = __builtin_amdgcn_mfma_f32_16x16x32_bf16(aU, bU, accU, 0, 0, 0);
        }
        float lam = (float)(*lam_ptr);
#pragma unroll
        for (int r = 0; r < 4; ++r) {
            int i = i0 + quad * 4 + r, j = j0 + col;
            int idx = i * NN + j;
            float p = (adj[idx] > 0 && i != j) ? expf(-lam * dist[idx]) : 0.f;
            out[idx] = p * (Vd[quad * 4 + r][col] + accW[r] + accU[r]);
        }
    }
}

extern "C" void kernel_launch(void* const* d_in, const int* in_sizes, int n_in,
                              void* d_out, int out_size, void* d_ws, size_t ws_size,
                              hipStream_t stream) {
    const float* od   = (const float*)d_in[0];
    const int*   adj  = (const int*)d_in[1];
    const float* dist = (const float*)d_in[2];
    const int*   lam  = (const int*)d_in[3];
    // d_in[4] = capacity (unused: max_iter=1, BPR update is post-output)
    float* out = (float*)d_out;

    unsigned short* P16  = (unsigned short*)d_ws;
    unsigned short* PT16 = P16 + NN * NN;

    build_p_kernel<<<NTILES, 256, 0, stream>>>(adj, dist, lam, P16, PT16);
    fused_tile_kernel<<<NTILES, 256, 0, stream>>>(P16, PT16, od, adj, dist, lam, out);
}

// Round 5
// 84.107 us; speedup vs baseline: 2.5432x; 1.5045x over previous
//
#include <hip/hip_runtime.h>
#include <math.h>

#define NN 384
#define NT 24              // NN/16
#define NTILES (NT * NT)   // 576

typedef __attribute__((ext_vector_type(8))) short short8;   // 8 bf16 (4 VGPRs)
typedef __attribute__((ext_vector_type(4))) float v4f;      // 4 fp32 acc

#define LOG2E 1.44269504088896340736f

__device__ __forceinline__ unsigned short f2bf(float f) {
    union { float f; unsigned u; } v; v.f = f;
    return (unsigned short)((v.u + 0x7FFFu + ((v.u >> 16) & 1u)) >> 16);
}
__device__ __forceinline__ float bf2f(unsigned short h) {
    union { unsigned u; float f; } v; v.u = ((unsigned)h) << 16;
    return v.f;
}

// K1: one wave per 16x16 tile of S = P*P. Builds its own A/B fragments from
// adj/dist (redundant exp, cheap); diagonal blocks also persist the fragments
// to P16/PT16 so K2 gets contiguous frag loads. Then V = od/(P+S) gated.
__global__ __launch_bounds__(64) void v_kernel(
    const float* __restrict__ dist, const int* __restrict__ adj,
    const float* __restrict__ od, const int* __restrict__ lam_ptr,
    unsigned short* __restrict__ P16, unsigned short* __restrict__ PT16,
    float* __restrict__ V32, unsigned short* __restrict__ V16,
    unsigned short* __restrict__ VT16)
{
    const int t = blockIdx.x;
    const int it = t / NT, jt = t % NT;
    const int i0 = it * 16, j0 = jt * 16;
    const int lane = threadIdx.x;
    const int col = lane & 15, quad = lane >> 4;
    const float lam = (float)(*lam_ptr);
    const float c = -lam * LOG2E;          // exp(-lam*d) = exp2(c*d)
    const int ir = i0 + col;               // this lane's A row
    const int jc = j0 + col;               // this lane's B column
    const bool diag = (it == jt);

    v4f acc = {0.f, 0.f, 0.f, 0.f};
#pragma unroll
    for (int k0 = 0; k0 < 12; ++k0) {
        const int kbase = k0 * 32 + quad * 8;
        // A-frag: P[ir][kbase..kbase+8)  (contiguous)
        float4 d0 = *(const float4*)(dist + ir * NN + kbase);
        float4 d1 = *(const float4*)(dist + ir * NN + kbase + 4);
        int4   a0 = *(const int4*)(adj + ir * NN + kbase);
        int4   a1 = *(const int4*)(adj + ir * NN + kbase + 4);
        float da[8] = {d0.x, d0.y, d0.z, d0.w, d1.x, d1.y, d1.z, d1.w};
        int   aa[8] = {a0.x, a0.y, a0.z, a0.w, a1.x, a1.y, a1.z, a1.w};
        short8 a, b;
#pragma unroll
        for (int e = 0; e < 8; ++e) {
            const int k = kbase + e;
            float pa = (aa[e] > 0 && ir != k) ? exp2f(c * da[e]) : 0.f;
            a[e] = (short)f2bf(pa);
            // B-frag: P[k][jc]  (stride-NN loads; coalesced across the 16-lane col group)
            float db = dist[k * NN + jc];
            int   ab = adj[k * NN + jc];
            float pb = (ab > 0 && k != jc) ? exp2f(c * db) : 0.f;
            b[e] = (short)f2bf(pb);
        }
        if (diag) {   // wave-uniform: persist P / P^T for the flows kernel
            *(short8*)(P16 + ir * NN + kbase) = a;
            *(short8*)(PT16 + jc * NN + kbase) = b;
        }
        acc = __builtin_amdgcn_mfma_f32_16x16x32_bf16(a, b, acc, 0, 0, 0);
    }

#pragma unroll
    for (int r = 0; r < 4; ++r) {
        const int i = i0 + quad * 4 + r, j = j0 + col;
        const int idx = i * NN + j;
        float p = (adj[idx] > 0 && i != j) ? exp2f(c * dist[idx]) : 0.f;
        p = bf2f(f2bf(p));                 // bf16-rounded, matching MFMA operand precision
        const float denom = p + acc[r];
        const float o = od[idx];
        const float v = (i != j && o > 0.f && denom > 0.f) ? o / denom : 0.f;
        V32[idx] = v;
        const unsigned short h = f2bf(v);
        V16[idx] = h;
        VT16[j * NN + i] = h;
    }
}

// K2: one wave per tile: W = V*P^T, U = P^T*V; out = p_exact*(V32 + W + U).
__global__ __launch_bounds__(64) void flows_kernel(
    const unsigned short* __restrict__ P16, const unsigned short* __restrict__ PT16,
    const unsigned short* __restrict__ V16, const unsigned short* __restrict__ VT16,
    const float* __restrict__ V32, const int* __restrict__ adj,
    const float* __restrict__ dist, const int* __restrict__ lam_ptr,
    float* __restrict__ out)
{
    const int t = blockIdx.x;
    const int i0 = (t / NT) * 16, j0 = (t % NT) * 16;
    const int lane = threadIdx.x;
    const int col = lane & 15, quad = lane >> 4;
    v4f accW = {0.f, 0.f, 0.f, 0.f};
    v4f accU = {0.f, 0.f, 0.f, 0.f};
    const short8* aW = (const short8*)(V16 + (i0 + col) * NN + quad * 8);
    const short8* bW = (const short8*)(P16 + (j0 + col) * NN + quad * 8);
    const short8* aU = (const short8*)(PT16 + (i0 + col) * NN + quad * 8);
    const short8* bU = (const short8*)(VT16 + (j0 + col) * NN + quad * 8);
#pragma unroll
    for (int k0 = 0; k0 < 12; ++k0) {
        short8 a0 = aW[k0 * 4];
        short8 b0 = bW[k0 * 4];
        short8 a1 = aU[k0 * 4];
        short8 b1 = bU[k0 * 4];
        accW = __builtin_amdgcn_mfma_f32_16x16x32_bf16(a0, b0, accW, 0, 0, 0);
        accU = __builtin_amdgcn_mfma_f32_16x16x32_bf16(a1, b1, accU, 0, 0, 0);
    }
    const float lam = (float)(*lam_ptr);
    const float c = -lam * LOG2E;
#pragma unroll
    for (int r = 0; r < 4; ++r) {
        const int i = i0 + quad * 4 + r, j = j0 + col;
        const int idx = i * NN + j;
        const float p = (adj[idx] > 0 && i != j) ? exp2f(c * dist[idx]) : 0.f;
        out[idx] = p * (V32[idx] + accW[r] + accU[r]);
    }
}

extern "C" void kernel_launch(void* const* d_in, const int* in_sizes, int n_in,
                              void* d_out, int out_size, void* d_ws, size_t ws_size,
                              hipStream_t stream) {
    const float* od   = (const float*)d_in[0];
    const int*   adj  = (const int*)d_in[1];
    const float* dist = (const float*)d_in[2];
    const int*   lam  = (const int*)d_in[3];
    // d_in[4] = capacity (unused: max_iter=1, BPR update is post-output)
    float* out = (float*)d_out;

    unsigned short* P16  = (unsigned short*)d_ws;
    unsigned short* PT16 = P16 + NN * NN;
    unsigned short* V16  = PT16 + NN * NN;
    unsigned short* VT16 = V16 + NN * NN;
    float*          V32  = (float*)(VT16 + NN * NN);

    v_kernel<<<NTILES, 64, 0, stream>>>(dist, adj, od, lam, P16, PT16, V32, V16, VT16);
    flows_kernel<<<NTILES, 64, 0, stream>>>(P16, PT16, V16, VT16, V32, adj, dist, lam, out);
}

// Round 6
// 79.980 us; speedup vs baseline: 2.6745x; 1.0516x over previous
//
#include <hip/hip_runtime.h>
#include <math.h>

#define NN 384
#define NT 24              // NN/16
#define NTILES (NT * NT)   // 576
#define LDSW 408           // padded LDS row stride (bf16): 816B rows, 16B-aligned,
                           // frag-read banks = col*12 mod 32 -> 2-way (free, m136)

typedef __attribute__((ext_vector_type(8))) short short8;            // 8 bf16
typedef __attribute__((ext_vector_type(4))) float v4f;               // 4 fp32
typedef __attribute__((ext_vector_type(4))) unsigned short ushort4v; // 8 B

#define LOG2E 1.44269504088896340736f

__device__ __forceinline__ unsigned short f2bf(float f) {
    union { float f; unsigned u; } v; v.f = f;
    return (unsigned short)((v.u + 0x7FFFu + ((v.u >> 16) & 1u)) >> 16);
}
__device__ __forceinline__ float bf2f(unsigned short h) {
    union { unsigned u; float f; } v; v.u = ((unsigned)h) << 16;
    return v.f;
}

// K1: one 4-wave block per 16x16 tile of S = P*P.
// Phase 1 (coalesced): stage P row-strip (As) and P col-strip (Bs, transposed)
// in LDS from adj/dist. Phase 2: K split across 4 waves (3 MFMAs each),
// LDS reduction, wave 0 epilogue V = od/(P+S). Diagonal blocks persist
// their strips to P16/PT16 for K2.
__global__ __launch_bounds__(256) void v_build_kernel(
    const float* __restrict__ dist, const int* __restrict__ adj,
    const float* __restrict__ od, const int* __restrict__ lam_ptr,
    unsigned short* __restrict__ P16, unsigned short* __restrict__ PT16,
    float* __restrict__ V32, unsigned short* __restrict__ V16,
    unsigned short* __restrict__ VT16)
{
    __shared__ __align__(16) unsigned short As[16][LDSW]; // P[i0+r][k]
    __shared__ __align__(16) unsigned short Bs[16][LDSW]; // P[k][j0+c] at [c][k]
    __shared__ v4f Sp[3][64];

    const int t = blockIdx.x;
    const int it = t / NT, jt = t % NT;
    const int i0 = it * 16, j0 = jt * 16;
    const int tid = threadIdx.x;
    const float lam = (float)(*lam_ptr);
    const float c = -lam * LOG2E;         // exp(-lam*d) = exp2(c*d)

    // ---- Phase 1a: row strip, rows i0..i0+15, all 384 cols (fully coalesced) ----
    {
        const int r = tid >> 4;           // 0..15
        const int cb = tid & 15;          // 0..15
        const int gi = i0 + r;
#pragma unroll
        for (int s = 0; s < 6; ++s) {
            const int c4 = (s * 16 + cb) * 4;
            float4 d4 = *(const float4*)(dist + gi * NN + c4);
            int4   a4 = *(const int4*)(adj + gi * NN + c4);
            ushort4v h;
            h[0] = (a4.x > 0 && gi != c4 + 0) ? f2bf(exp2f(c * d4.x)) : 0;
            h[1] = (a4.y > 0 && gi != c4 + 1) ? f2bf(exp2f(c * d4.y)) : 0;
            h[2] = (a4.z > 0 && gi != c4 + 2) ? f2bf(exp2f(c * d4.z)) : 0;
            h[3] = (a4.w > 0 && gi != c4 + 3) ? f2bf(exp2f(c * d4.w)) : 0;
            *(ushort4v*)&As[r][c4] = h;
        }
    }
    // ---- Phase 1b: col strip, all 384 rows, cols j0..j0+15 (coalesced loads) ----
    {
        const int c4 = (tid & 3) * 4;     // 0,4,8,12
        const int r0 = tid >> 2;          // 0..63
#pragma unroll
        for (int p = 0; p < 6; ++p) {
            const int rr = r0 + p * 64;
            float4 d4 = *(const float4*)(dist + rr * NN + j0 + c4);
            int4   a4 = *(const int4*)(adj + rr * NN + j0 + c4);
            Bs[c4 + 0][rr] = (a4.x > 0 && rr != j0 + c4 + 0) ? f2bf(exp2f(c * d4.x)) : 0;
            Bs[c4 + 1][rr] = (a4.y > 0 && rr != j0 + c4 + 1) ? f2bf(exp2f(c * d4.y)) : 0;
            Bs[c4 + 2][rr] = (a4.z > 0 && rr != j0 + c4 + 2) ? f2bf(exp2f(c * d4.z)) : 0;
            Bs[c4 + 3][rr] = (a4.w > 0 && rr != j0 + c4 + 3) ? f2bf(exp2f(c * d4.w)) : 0;
        }
    }
    __syncthreads();

    // ---- Phase 2: K-split MFMA (wave w covers k in [96w, 96w+96)) ----
    const int wave = tid >> 6, lane = tid & 63;
    const int col = lane & 15, quad = lane >> 4;
    v4f acc = {0.f, 0.f, 0.f, 0.f};
#pragma unroll
    for (int kk = 0; kk < 3; ++kk) {
        const int kbase = (wave * 3 + kk) * 32 + quad * 8;
        short8 a = *(const short8*)&As[col][kbase];
        short8 b = *(const short8*)&Bs[col][kbase];
        acc = __builtin_amdgcn_mfma_f32_16x16x32_bf16(a, b, acc, 0, 0, 0);
    }
    if (wave) Sp[wave - 1][lane] = acc;
    __syncthreads();

    if (wave == 0) {
        acc += Sp[0][lane];
        acc += Sp[1][lane];
        acc += Sp[2][lane];
#pragma unroll
        for (int r = 0; r < 4; ++r) {
            const int i = i0 + quad * 4 + r, j = j0 + col;
            const int idx = i * NN + j;
            const float p = bf2f(As[quad * 4 + r][j]);  // bf16-rounded P[i][j]
            const float denom = p + acc[r];
            const float o = od[idx];
            const float v = (i != j && o > 0.f && denom > 0.f) ? o / denom : 0.f;
            V32[idx] = v;
            const unsigned short h = f2bf(v);
            V16[idx] = h;
            VT16[j * NN + i] = h;
        }
    }

    // ---- Persist P / P^T strips (diagonal blocks only; As/Bs stable) ----
    if (it == jt) {
        const int r = tid >> 4, cb = tid & 15;
#pragma unroll
        for (int s = 0; s < 6; ++s) {
            const int c4 = (s * 16 + cb) * 4;
            *(ushort4v*)(P16 + (i0 + r) * NN + c4) = *(const ushort4v*)&As[r][c4];
            *(ushort4v*)(PT16 + (j0 + r) * NN + c4) = *(const ushort4v*)&Bs[r][c4];
        }
    }
}

// K2: one 4-wave block per tile, K-split: W = V*P^T, U = P^T*V;
// out = p_exact * (V32 + W + U).
__global__ __launch_bounds__(256) void flows_kernel(
    const unsigned short* __restrict__ P16, const unsigned short* __restrict__ PT16,
    const unsigned short* __restrict__ V16, const unsigned short* __restrict__ VT16,
    const float* __restrict__ V32, const int* __restrict__ adj,
    const float* __restrict__ dist, const int* __restrict__ lam_ptr,
    float* __restrict__ out)
{
    __shared__ v4f SpW[3][64];
    __shared__ v4f SpU[3][64];

    const int t = blockIdx.x;
    const int i0 = (t / NT) * 16, j0 = (t % NT) * 16;
    const int tid = threadIdx.x;
    const int wave = tid >> 6, lane = tid & 63;
    const int col = lane & 15, quad = lane >> 4;

    v4f accW = {0.f, 0.f, 0.f, 0.f};
    v4f accU = {0.f, 0.f, 0.f, 0.f};
    const short8* aW = (const short8*)(V16 + (i0 + col) * NN + quad * 8);
    const short8* bW = (const short8*)(P16 + (j0 + col) * NN + quad * 8);
    const short8* aU = (const short8*)(PT16 + (i0 + col) * NN + quad * 8);
    const short8* bU = (const short8*)(VT16 + (j0 + col) * NN + quad * 8);
#pragma unroll
    for (int kk = 0; kk < 3; ++kk) {
        const int k4 = (wave * 3 + kk) * 4;   // short8 index: k0*32 elems / 8
        short8 a0 = aW[k4];
        short8 b0 = bW[k4];
        short8 a1 = aU[k4];
        short8 b1 = bU[k4];
        accW = __builtin_amdgcn_mfma_f32_16x16x32_bf16(a0, b0, accW, 0, 0, 0);
        accU = __builtin_amdgcn_mfma_f32_16x16x32_bf16(a1, b1, accU, 0, 0, 0);
    }
    if (wave) { SpW[wave - 1][lane] = accW; SpU[wave - 1][lane] = accU; }
    __syncthreads();

    if (wave == 0) {
#pragma unroll
        for (int q = 0; q < 3; ++q) { accW += SpW[q][lane]; accU += SpU[q][lane]; }
        const float lam = (float)(*lam_ptr);
        const float c = -lam * LOG2E;
#pragma unroll
        for (int r = 0; r < 4; ++r) {
            const int i = i0 + quad * 4 + r, j = j0 + col;
            const int idx = i * NN + j;
            const float p = (adj[idx] > 0 && i != j) ? exp2f(c * dist[idx]) : 0.f;
            out[idx] = p * (V32[idx] + accW[r] + accU[r]);
        }
    }
}

extern "C" void kernel_launch(void* const* d_in, const int* in_sizes, int n_in,
                              void* d_out, int out_size, void* d_ws, size_t ws_size,
                              hipStream_t stream) {
    const float* od   = (const float*)d_in[0];
    const int*   adj  = (const int*)d_in[1];
    const float* dist = (const float*)d_in[2];
    const int*   lam  = (const int*)d_in[3];
    // d_in[4] = capacity (unused: max_iter=1, BPR update is post-output)
    float* out = (float*)d_out;

    unsigned short* P16  = (unsigned short*)d_ws;
    unsigned short* PT16 = P16 + NN * NN;
    unsigned short* V16  = PT16 + NN * NN;
    unsigned short* VT16 = V16 + NN * NN;
    float*          V32  = (float*)(VT16 + NN * NN);

    v_build_kernel<<<NTILES, 256, 0, stream>>>(dist, adj, od, lam, P16, PT16, V32, V16, VT16);
    flows_kernel<<<NTILES, 256, 0, stream>>>(P16, PT16, V16, VT16, V32, adj, dist, lam, out);
}